// Round 1
// baseline (389.741 us; speedup 1.0000x reference)
//
#include <hip/hip_runtime.h>
#include <cstdint>

// Problem constants
#define NB   256    // batch
#define EPSF 1e-5f
#define SCALEF 0.25f  // D^-0.5

// ws layout (bytes):
//   F   : f32 [64][256][128]      @ 0          (8,388,608 B)
//   kv  : bf16 [256][8192][16]    @ 8,388,608  (67,108,864 B)
//   q2  : f32 [256][32][16]       @ 75,497,472 (524,288 B)

__device__ __forceinline__ float bf2f(uint32_t u){
    union { uint32_t i; float f; } v; v.i = u << 16; return v.f;
}
__device__ __forceinline__ uint32_t f2bf(float f){
    union { float f; uint32_t i; } v; v.f = f;
    return (v.i + 0x7FFFu + ((v.i >> 16) & 1u)) >> 16;  // RNE, no NaN care needed
}

// ---------------------------------------------------------------------------
// Kernel 1: fused weight F[n2][x*16+dd][h] = sum_c Wc[(n2&3)*16+x][dd&3][c] *
//           E[n2][x*16 + (dd>>2)*4 + c][h]
// grid 1024 (n2*16+x), block 128 (h)
// ---------------------------------------------------------------------------
__global__ void k_fuseF(const float* __restrict__ wc, const float* __restrict__ E,
                        float* __restrict__ F){
    const int blk = blockIdx.x;
    const int n2 = blk >> 4, x = blk & 15;
    const int h = threadIdx.x;
    const int j = (n2 & 3) * 16 + x;
    float w[16];
#pragma unroll
    for (int t = 0; t < 16; ++t) w[t] = wc[j * 16 + t];
    const float* Eb = E + ((size_t)n2 * 256 + x * 16) * 128 + h;
    float e[16];
#pragma unroll
    for (int t = 0; t < 16; ++t) e[t] = Eb[(size_t)t * 128];
    float* Fb = F + ((size_t)n2 * 256 + x * 16) * 128 + h;
#pragma unroll
    for (int dd = 0; dd < 16; ++dd){
        const int r = dd >> 2, k = dd & 3;
        float acc = 0.f;
#pragma unroll
        for (int c = 0; c < 4; ++c) acc += w[k * 4 + c] * e[r * 4 + c];
        Fb[(size_t)dd * 128] = acc;
    }
}

// ---------------------------------------------------------------------------
// Kernel 2: q2[b][o][r*4+c] = SCALE * sum_k wn[o][r][k] * next_pose[b][o][k*4+c]
// grid 256 (b), block 512
// ---------------------------------------------------------------------------
__global__ void k_q2(const float* __restrict__ npse, const float* __restrict__ wn,
                     float* __restrict__ q2g){
    const int b = blockIdx.x;
    const int t = threadIdx.x;           // 0..511
    const int o = t >> 4, d = t & 15, r = d >> 2, c = d & 3;
    float acc = 0.f;
#pragma unroll
    for (int k = 0; k < 4; ++k)
        acc += wn[o * 16 + r * 4 + k] * npse[((size_t)b * 32 + o) * 16 + k * 4 + c];
    q2g[(size_t)b * 512 + t] = acc * SCALEF;
}

// ---------------------------------------------------------------------------
// Kernel 3: main GEMM.  Per n2: K[b][d2][h] = cp_row(b, i, y, 0:256) . F[n2][:][h]
//   i = d2*4 + (n2>>4), y = n2&15.
// Output scattered to kv[b][n2*128+h][d2] as bf16.
// Tile: 256 rows (m = b*16+d2) x 128 cols (h), K = 256, K-step 16.
// block 256 threads; thread micro-tile 16 rows x 8 cols.
// Lane map: tr = (tid&3)|((tid>>6)<<2), tc = (tid>>2)&15  (keeps LDS reads ~2-way)
// grid (16, 64)
// ---------------------------------------------------------------------------
#define KT  16
#define AST 260   // transposed-A LDS row stride (floats); 260*4B % 16B == 0

__global__ __launch_bounds__(256, 2) void k_gemm(const float* __restrict__ cp,
                                                 const float* __restrict__ F,
                                                 uint16_t* __restrict__ kv){
    __shared__ __align__(16) float As[KT * AST];   // As[kk][row]
    __shared__ __align__(16) float Fs[KT * 128];   // Fs[kk][h]
    const int tid = threadIdx.x;
    const int mtile = blockIdx.x;       // 0..15
    const int n2 = blockIdx.y;          // 0..63
    const int n2h = n2 >> 4, y = n2 & 15;
    const int tr = (tid & 3) | ((tid >> 6) << 2);  // 0..15
    const int tc = (tid >> 2) & 15;                // 0..15

    float acc[16][8];
#pragma unroll
    for (int u = 0; u < 16; ++u)
#pragma unroll
        for (int v = 0; v < 8; ++v) acc[u][v] = 0.f;

    // Pre-compute the 4 global row bases this thread loads each K-step.
    const float* abase[4];
#pragma unroll
    for (int p = 0; p < 4; ++p){
        const int idx = tid + p * 256;
        const int row = idx >> 2;            // 0..255
        const int c4  = idx & 3;             // 0..3
        const int b   = (mtile << 4) | (row >> 4);
        const int d2  = row & 15;
        const int i   = d2 * 4 + n2h;
        abase[p] = cp + (size_t)b * 262144 + (size_t)i * 4096 + (size_t)y * 256 + c4 * 4;
    }
    const float* fbase = F + ((size_t)n2 * 256) * 128;

    for (int kt = 0; kt < 16; ++kt){
        // stage A (transposed) : 256 rows x 16 K-floats
#pragma unroll
        for (int p = 0; p < 4; ++p){
            const int idx = tid + p * 256;
            const int row = idx >> 2;
            const int c4  = idx & 3;
            const float4 v4 = *(const float4*)(abase[p] + kt * 16);
            const int kk0 = c4 * 4;
            As[(kk0 + 0) * AST + row] = v4.x;
            As[(kk0 + 1) * AST + row] = v4.y;
            As[(kk0 + 2) * AST + row] = v4.z;
            As[(kk0 + 3) * AST + row] = v4.w;
        }
        // stage F : 16 rows x 128
#pragma unroll
        for (int p = 0; p < 2; ++p){
            const int idx = tid + p * 256;
            const int fr = idx >> 5;
            const int c4 = idx & 31;
            *(float4*)(Fs + fr * 128 + c4 * 4) =
                *(const float4*)(fbase + ((size_t)(kt * 16 + fr)) * 128 + c4 * 4);
        }
        __syncthreads();
#pragma unroll
        for (int kk = 0; kk < KT; ++kk){
            float a[16], f[8];
            float4 t0 = *(const float4*)(As + kk * AST + tr * 16 + 0);
            float4 t1 = *(const float4*)(As + kk * AST + tr * 16 + 4);
            float4 t2 = *(const float4*)(As + kk * AST + tr * 16 + 8);
            float4 t3 = *(const float4*)(As + kk * AST + tr * 16 + 12);
            a[0]=t0.x; a[1]=t0.y; a[2]=t0.z; a[3]=t0.w;
            a[4]=t1.x; a[5]=t1.y; a[6]=t1.z; a[7]=t1.w;
            a[8]=t2.x; a[9]=t2.y; a[10]=t2.z; a[11]=t2.w;
            a[12]=t3.x; a[13]=t3.y; a[14]=t3.z; a[15]=t3.w;
            float4 g0 = *(const float4*)(Fs + kk * 128 + tc * 8 + 0);
            float4 g1 = *(const float4*)(Fs + kk * 128 + tc * 8 + 4);
            f[0]=g0.x; f[1]=g0.y; f[2]=g0.z; f[3]=g0.w;
            f[4]=g1.x; f[5]=g1.y; f[6]=g1.z; f[7]=g1.w;
#pragma unroll
            for (int u = 0; u < 16; ++u)
#pragma unroll
                for (int v = 0; v < 8; ++v) acc[u][v] += a[u] * f[v];
        }
        __syncthreads();
    }

    // Epilogue: thread's 16 rows are d2 = 0..15 of b = mtile*16 + tr, so each
    // (v) column owns a full 16-element kv row -> pack to 2x uint4 (32 B).
    const int bb = mtile * 16 + tr;
#pragma unroll
    for (int v = 0; v < 8; ++v){
        uint32_t pk[8];
#pragma unroll
        for (int q = 0; q < 8; ++q){
            const uint32_t lo = f2bf(acc[q * 2 + 0][v]);
            const uint32_t hi = f2bf(acc[q * 2 + 1][v]);
            pk[q] = lo | (hi << 16);
        }
        uint4* dst = (uint4*)(kv + ((size_t)bb * 8192 + n2 * 128 + tc * 8 + v) * 16);
        dst[0] = make_uint4(pk[0], pk[1], pk[2], pk[3]);
        dst[1] = make_uint4(pk[4], pk[5], pk[6], pk[7]);
    }
}

// ---------------------------------------------------------------------------
// Kernel 4: routing + epilogue, one block per batch b, 512 threads.
// Chunked over n (512/chunk, 16 chunks):
//   phase A: thread t owns n = cb+t: load kv row, logits vs q2 (global, uniform
//            -> scalar loads), per-n softmax over 32 parents, stash w to LDS.
//   phase B: thread owns (slice=t>>5, j-pair, e-oct): 2x8 register tile over
//            its 32 n's.
// Then slice reduction, parent pose transform (w_next), LayerNorm, store.
// ---------------------------------------------------------------------------
__global__ __launch_bounds__(512) void k_attn(const uint16_t* __restrict__ kv,
                                              const float* __restrict__ q2g,
                                              const float* __restrict__ wn,
                                              const float* __restrict__ lnw,
                                              const float* __restrict__ lnb,
                                              float* __restrict__ out){
    __shared__ __align__(16) float smem[27168];
    float* kvs = smem;            // [512][20]
    float* wl  = smem + 10240;    // [32][513]
    float* red = smem + 10240;    // alias wl after final barrier: [16][32][16]
    float* cnd = smem + 26656;    // [32][16]

    const int b = blockIdx.x;
    const int t = threadIdx.x;
    const int sl = t >> 5, l = t & 31;
    const int jp = l >> 1, ep = l & 1;
    const int j0 = jp * 2;
    const float* q2b = q2g + (size_t)b * 512;

    float c2[2][8];
#pragma unroll
    for (int a = 0; a < 2; ++a)
#pragma unroll
        for (int v = 0; v < 8; ++v) c2[a][v] = 0.f;

    for (int cb = 0; cb < 8192; cb += 512){
        __syncthreads();   // protect kvs/wl against previous phase B readers
        // ---- phase A ----
        const int n = cb + t;
        const uint4* kp = (const uint4*)(kv + ((size_t)b * 8192 + n) * 16);
        const uint4 k0 = kp[0], k1 = kp[1];
        float kvr[16];
        kvr[0]  = bf2f(k0.x & 0xFFFFu); kvr[1]  = bf2f(k0.x >> 16);
        kvr[2]  = bf2f(k0.y & 0xFFFFu); kvr[3]  = bf2f(k0.y >> 16);
        kvr[4]  = bf2f(k0.z & 0xFFFFu); kvr[5]  = bf2f(k0.z >> 16);
        kvr[6]  = bf2f(k0.w & 0xFFFFu); kvr[7]  = bf2f(k0.w >> 16);
        kvr[8]  = bf2f(k1.x & 0xFFFFu); kvr[9]  = bf2f(k1.x >> 16);
        kvr[10] = bf2f(k1.y & 0xFFFFu); kvr[11] = bf2f(k1.y >> 16);
        kvr[12] = bf2f(k1.z & 0xFFFFu); kvr[13] = bf2f(k1.z >> 16);
        kvr[14] = bf2f(k1.w & 0xFFFFu); kvr[15] = bf2f(k1.w >> 16);
#pragma unroll
        for (int e = 0; e < 16; e += 2)
            *(float2*)(kvs + t * 20 + e) = make_float2(kvr[e], kvr[e + 1]);

        float lg[32];
#pragma unroll
        for (int j = 0; j < 32; ++j){
            const float* q2r = q2b + j * 16;
            float s = 0.f;
#pragma unroll
            for (int e = 0; e < 16; ++e) s += q2r[e] * kvr[e];
            lg[j] = s;
        }
        float m = lg[0];
#pragma unroll
        for (int j = 1; j < 32; ++j) m = fmaxf(m, lg[j]);
        float s = 0.f;
#pragma unroll
        for (int j = 0; j < 32; ++j){ lg[j] = __expf(lg[j] - m); s += lg[j]; }
        const float inv = 1.f / s;
#pragma unroll
        for (int j = 0; j < 32; ++j) wl[j * 513 + t] = lg[j] * inv;
        __syncthreads();
        // ---- phase B ----
#pragma unroll 4
        for (int it = 0; it < 32; ++it){
            const int nn = sl * 32 + it;
            const float w0 = wl[j0 * 513 + nn];
            const float w1 = wl[j0 * 513 + 513 + nn];
            const float4 ka = *(const float4*)(kvs + nn * 20 + ep * 8);
            const float4 kb = *(const float4*)(kvs + nn * 20 + ep * 8 + 4);
            c2[0][0] += w0 * ka.x; c2[0][1] += w0 * ka.y;
            c2[0][2] += w0 * ka.z; c2[0][3] += w0 * ka.w;
            c2[0][4] += w0 * kb.x; c2[0][5] += w0 * kb.y;
            c2[0][6] += w0 * kb.z; c2[0][7] += w0 * kb.w;
            c2[1][0] += w1 * ka.x; c2[1][1] += w1 * ka.y;
            c2[1][2] += w1 * ka.z; c2[1][3] += w1 * ka.w;
            c2[1][4] += w1 * kb.x; c2[1][5] += w1 * kb.y;
            c2[1][6] += w1 * kb.z; c2[1][7] += w1 * kb.w;
        }
    }
    __syncthreads();
    // slice partials -> LDS (aliases wl; all wl reads are done)
#pragma unroll
    for (int jj = 0; jj < 2; ++jj)
#pragma unroll
        for (int v = 0; v < 8; ++v)
            red[(sl * 32 + (j0 + jj)) * 16 + ep * 8 + v] = c2[jj][v];
    __syncthreads();
    {   // reduce 16 slices -> cnd[32][16]
        const int j = t >> 4, e = t & 15;
        float sum = 0.f;
#pragma unroll
        for (int s2 = 0; s2 < 16; ++s2) sum += red[(s2 * 32 + j) * 16 + e];
        cnd[j * 16 + e] = sum;
    }
    __syncthreads();
    if (t < 32){
        const int o = t;
        float m2[16];
#pragma unroll
        for (int r = 0; r < 4; ++r)
#pragma unroll
            for (int c = 0; c < 4; ++c){
                float a = 0.f;
#pragma unroll
                for (int k = 0; k < 4; ++k)
                    a += wn[o * 16 + r * 4 + k] * cnd[o * 16 + k * 4 + c];
                m2[r * 4 + c] = a;
            }
        float mu = 0.f;
#pragma unroll
        for (int e = 0; e < 16; ++e) mu += m2[e];
        mu *= (1.f / 16.f);
        float var = 0.f;
#pragma unroll
        for (int e = 0; e < 16; ++e){ const float d = m2[e] - mu; var += d * d; }
        var *= (1.f / 16.f);
        const float invs = rsqrtf(var + EPSF);
#pragma unroll
        for (int e = 0; e < 16; ++e)
            out[(size_t)b * 512 + o * 16 + e] = (m2[e] - mu) * invs * lnw[e] + lnb[e];
    }
}

// ---------------------------------------------------------------------------
extern "C" void kernel_launch(void* const* d_in, const int* in_sizes, int n_in,
                              void* d_out, int out_size, void* d_ws, size_t ws_size,
                              hipStream_t stream){
    const float* cp   = (const float*)d_in[0];   // current_pose [256][64][16][16][16]
    const float* npse = (const float*)d_in[1];   // next_pose    [256][32][16]
    const float* wc   = (const float*)d_in[2];   // w_current    [64][4][4]
    const float* wn   = (const float*)d_in[3];   // w_next       [32][4][4]
    const float* E    = (const float*)d_in[4];   // E_proj       [64][256][128]
    const float* lnw  = (const float*)d_in[5];   // ln_weight    [16]
    const float* lnb  = (const float*)d_in[6];   // ln_bias      [16]
    float* out = (float*)d_out;

    char* ws = (char*)d_ws;
    float*    F   = (float*)ws;                              // 8,388,608 B
    uint16_t* kvb = (uint16_t*)(ws + 8388608);               // 67,108,864 B
    float*    q2g = (float*)(ws + 8388608 + 67108864);       // 524,288 B

    hipLaunchKernelGGL(k_fuseF, dim3(1024), dim3(128), 0, stream, wc, E, F);
    hipLaunchKernelGGL(k_q2,    dim3(256),  dim3(512), 0, stream, npse, wn, q2g);
    hipLaunchKernelGGL(k_gemm,  dim3(16, 64), dim3(256), 0, stream, cp, F, kvb);
    hipLaunchKernelGGL(k_attn,  dim3(256),  dim3(512), 0, stream, kvb, q2g, wn, lnw, lnb, out);
}

// Round 2
// 204.179 us; speedup vs baseline: 1.9088x; 1.9088x over previous
//
#include <hip/hip_runtime.h>
#include <cstdint>

#define EPSF 1e-5f
#define SCALEF 0.25f  // D^-0.5

typedef __attribute__((ext_vector_type(8))) short bf16x8;   // 8 bf16 = 4 VGPR
typedef __attribute__((ext_vector_type(4))) float f32x4;

__device__ __forceinline__ float bf2f(uint32_t u){
    union { uint32_t i; float f; } v; v.i = u << 16; return v.f;
}
__device__ __forceinline__ uint32_t f2bf(float f){
    union { float f; uint32_t i; } v; v.f = f;
    return (v.i + 0x7FFFu + ((v.i >> 16) & 1u)) >> 16;  // RNE
}

// ws layout (bytes):
//   Ft  : bf16 [64][128 h][256 k]   @ 0           (4,194,304 B)
//   kv  : bf16 [256][8192][16]      @ 4,194,304   (67,108,864 B)
//   q2  : f32  [256][32][16]        @ 71,303,168  (524,288 B)

// ---------------------------------------------------------------------------
// Kernel 1: fused weight, transposed+bf16:
//   Ft[n2][h][x*16+dd] = bf16( sum_c Wc[(n2&3)*16+x][dd&3][c] *
//                               E[n2][x*16 + (dd>>2)*4 + c][h] )
// grid 1024 (n2*16+x), block 128 (h)
// ---------------------------------------------------------------------------
__global__ void k_fuseF(const float* __restrict__ wc, const float* __restrict__ E,
                        unsigned short* __restrict__ Ft){
    const int blk = blockIdx.x;
    const int n2 = blk >> 4, x = blk & 15;
    const int h = threadIdx.x;
    const int j = (n2 & 3) * 16 + x;
    float w[16];
#pragma unroll
    for (int t = 0; t < 16; ++t) w[t] = wc[j * 16 + t];
    const float* Eb = E + ((size_t)n2 * 256 + x * 16) * 128 + h;
    float e[16];
#pragma unroll
    for (int t = 0; t < 16; ++t) e[t] = Eb[(size_t)t * 128];
    uint32_t pk[8];
#pragma unroll
    for (int q = 0; q < 8; ++q){
        uint32_t both[2];
#pragma unroll
        for (int half = 0; half < 2; ++half){
            const int dd = q * 2 + half;
            const int r = dd >> 2, k = dd & 3;
            float acc = 0.f;
#pragma unroll
            for (int c = 0; c < 4; ++c) acc += w[k * 4 + c] * e[r * 4 + c];
            both[half] = f2bf(acc);
        }
        pk[q] = both[0] | (both[1] << 16);
    }
    unsigned short* dst = Ft + (size_t)n2 * 32768 + (size_t)h * 256 + x * 16;
    ((uint4*)dst)[0] = make_uint4(pk[0], pk[1], pk[2], pk[3]);
    ((uint4*)dst)[1] = make_uint4(pk[4], pk[5], pk[6], pk[7]);
}

// ---------------------------------------------------------------------------
// Kernel 2: q2[b][o][r*4+c] = SCALE * sum_k wn[o][r][k] * next_pose[b][o][k*4+c]
// ---------------------------------------------------------------------------
__global__ void k_q2(const float* __restrict__ npse, const float* __restrict__ wn,
                     float* __restrict__ q2g){
    const int b = blockIdx.x;
    const int t = threadIdx.x;           // 0..511
    const int o = t >> 4, d = t & 15, r = d >> 2, c = d & 3;
    float acc = 0.f;
#pragma unroll
    for (int k = 0; k < 4; ++k)
        acc += wn[o * 16 + r * 4 + k] * npse[((size_t)b * 32 + o) * 16 + k * 4 + c];
    q2g[(size_t)b * 512 + t] = acc * SCALEF;
}

// ---------------------------------------------------------------------------
// Kernel 3: MFMA GEMM.  Per n2: K[b][d2][h] = cp_row(b,i,y,0:256) . Ft[n2][h][:]
//   i = d2*4 + (n2>>4), y = n2&15.
// Block tile 128(m) x 128(h), K=256, K-step 32, 4 waves (2x2), wave-tile 64x64.
// A reg-staged fp32->bf16; B (Ft) already bf16. LDS [row][32k] bf16, 64B rows,
// XOR swizzle slot ^= (row>>1)&3  -> 2-way (free) ds_read_b128 frag reads.
// grid (32 mtiles, 64 n2), block 256.
// ---------------------------------------------------------------------------
__global__ __launch_bounds__(256, 3) void k_gemm(const float* __restrict__ cp,
                                                 const unsigned short* __restrict__ Ft,
                                                 unsigned short* __restrict__ kv){
    __shared__ unsigned short As[2][128 * 32];
    __shared__ unsigned short Fs[2][128 * 32];
    const int tid  = threadIdx.x;
    const int lane = tid & 63;
    const int wave = tid >> 6;              // 0..3
    const int wm = wave >> 1, wn = wave & 1;
    const int l15 = lane & 15, g = lane >> 4;
    const int mtile = blockIdx.x;           // 0..31
    const int n2 = blockIdx.y;              // 0..63
    const int n2h = n2 >> 4, y = n2 & 15;

    // ---- A staging map: 4 x float4 per thread per K-step ----
    const float* abase[4];
    int aoff[4];
#pragma unroll
    for (int p = 0; p < 4; ++p){
        const int idx = tid + p * 256;      // 0..1023
        const int m = idx >> 3;             // 0..127
        const int kq = idx & 7;             // k = kq*4
        const int b = mtile * 8 + (m >> 4);
        const int i = (m & 15) * 4 + n2h;
        abase[p] = cp + (size_t)b * 262144 + (size_t)i * 4096 + (size_t)y * 256 + kq * 4;
        aoff[p] = m * 32 + (((kq >> 1) ^ ((m >> 1) & 3)) * 8) + (kq & 1) * 4;
    }
    // ---- B staging map: 2 x uint4 (8 bf16) per thread per K-step ----
    const unsigned short* bbase[2];
    int boff[2];
#pragma unroll
    for (int p = 0; p < 2; ++p){
        const int idx = tid + p * 256;      // 0..511
        const int h = idx >> 2;             // 0..127
        const int kq4 = idx & 3;            // k = kq4*8
        bbase[p] = Ft + (size_t)n2 * 32768 + (size_t)h * 256 + kq4 * 8;
        boff[p] = h * 32 + ((kq4 ^ ((h >> 1) & 3)) * 8);
    }
    // ---- fragment read offsets ----
    int afoff[4], bfoff[4];
#pragma unroll
    for (int mf = 0; mf < 4; ++mf){
        const int row = wm * 64 + mf * 16 + l15;
        afoff[mf] = row * 32 + ((g ^ ((row >> 1) & 3)) * 8);
    }
#pragma unroll
    for (int nf = 0; nf < 4; ++nf){
        const int row = wn * 64 + nf * 16 + l15;
        bfoff[nf] = row * 32 + ((g ^ ((row >> 1) & 3)) * 8);
    }

    f32x4 acc[4][4];
#pragma unroll
    for (int mf = 0; mf < 4; ++mf)
#pragma unroll
        for (int nf = 0; nf < 4; ++nf) acc[mf][nf] = (f32x4){0.f, 0.f, 0.f, 0.f};

    float4 av[4];
    uint4  bv[2];
    // ---- prologue: stage kt=0 into buf 0 ----
#pragma unroll
    for (int p = 0; p < 4; ++p) av[p] = *(const float4*)(abase[p]);
#pragma unroll
    for (int p = 0; p < 2; ++p) bv[p] = *(const uint4*)(bbase[p]);
#pragma unroll
    for (int p = 0; p < 4; ++p){
        ushort4 w4;
        w4.x = (unsigned short)f2bf(av[p].x);
        w4.y = (unsigned short)f2bf(av[p].y);
        w4.z = (unsigned short)f2bf(av[p].z);
        w4.w = (unsigned short)f2bf(av[p].w);
        *(ushort4*)(&As[0][aoff[p]]) = w4;
    }
#pragma unroll
    for (int p = 0; p < 2; ++p) *(uint4*)(&Fs[0][boff[p]]) = bv[p];
    __syncthreads();

    for (int kt = 0; kt < 8; ++kt){
        const int cur = kt & 1;
        if (kt < 7){                        // issue next-tile global loads early
#pragma unroll
            for (int p = 0; p < 4; ++p) av[p] = *(const float4*)(abase[p] + (kt + 1) * 32);
#pragma unroll
            for (int p = 0; p < 2; ++p) bv[p] = *(const uint4*)(bbase[p] + (kt + 1) * 32);
        }
        // compute current buffer
        bf16x8 af[4], bfr[4];
#pragma unroll
        for (int mf = 0; mf < 4; ++mf) af[mf] = *(const bf16x8*)(&As[cur][afoff[mf]]);
#pragma unroll
        for (int nf = 0; nf < 4; ++nf) bfr[nf] = *(const bf16x8*)(&Fs[cur][bfoff[nf]]);
#pragma unroll
        for (int nf = 0; nf < 4; ++nf)
#pragma unroll
            for (int mf = 0; mf < 4; ++mf)
                acc[mf][nf] = __builtin_amdgcn_mfma_f32_16x16x32_bf16(af[mf], bfr[nf], acc[mf][nf], 0, 0, 0);
        if (kt < 7){                        // write next tile into the free buffer
            const int nxt = cur ^ 1;
#pragma unroll
            for (int p = 0; p < 4; ++p){
                ushort4 w4;
                w4.x = (unsigned short)f2bf(av[p].x);
                w4.y = (unsigned short)f2bf(av[p].y);
                w4.z = (unsigned short)f2bf(av[p].z);
                w4.w = (unsigned short)f2bf(av[p].w);
                *(ushort4*)(&As[nxt][aoff[p]]) = w4;
            }
#pragma unroll
            for (int p = 0; p < 2; ++p) *(uint4*)(&Fs[nxt][boff[p]]) = bv[p];
        }
        __syncthreads();
    }

    // ---- epilogue: C/D frag (col=lane&15, row=(lane>>4)*4+r); r -> d2 consecutive
#pragma unroll
    for (int mf = 0; mf < 4; ++mf)
#pragma unroll
        for (int nf = 0; nf < 4; ++nf){
            ushort4 pk;
            pk.x = (unsigned short)f2bf(acc[mf][nf][0]);
            pk.y = (unsigned short)f2bf(acc[mf][nf][1]);
            pk.z = (unsigned short)f2bf(acc[mf][nf][2]);
            pk.w = (unsigned short)f2bf(acc[mf][nf][3]);
            const size_t base =
                ((size_t)(mtile * 8 + wm * 4 + mf) * 8192 +
                 (size_t)n2 * 128 + wn * 64 + nf * 16 + l15) * 16 + g * 4;
            *(ushort4*)(kv + base) = pk;
        }
}

// ---------------------------------------------------------------------------
// Kernel 4: routing + epilogue (unchanged from round 1)
// ---------------------------------------------------------------------------
__global__ __launch_bounds__(512) void k_attn(const unsigned short* __restrict__ kv,
                                              const float* __restrict__ q2g,
                                              const float* __restrict__ wn,
                                              const float* __restrict__ lnw,
                                              const float* __restrict__ lnb,
                                              float* __restrict__ out){
    __shared__ __align__(16) float smem[27168];
    float* kvs = smem;            // [512][20]
    float* wl  = smem + 10240;    // [32][513]
    float* red = smem + 10240;    // alias wl after final barrier: [16][32][16]
    float* cnd = smem + 26656;    // [32][16]

    const int b = blockIdx.x;
    const int t = threadIdx.x;
    const int sl = t >> 5, l = t & 31;
    const int jp = l >> 1, ep = l & 1;
    const int j0 = jp * 2;
    const float* q2b = q2g + (size_t)b * 512;

    float c2[2][8];
#pragma unroll
    for (int a = 0; a < 2; ++a)
#pragma unroll
        for (int v = 0; v < 8; ++v) c2[a][v] = 0.f;

    for (int cb = 0; cb < 8192; cb += 512){
        __syncthreads();
        // ---- phase A ----
        const int n = cb + t;
        const uint4* kp = (const uint4*)(kv + ((size_t)b * 8192 + n) * 16);
        const uint4 k0 = kp[0], k1 = kp[1];
        float kvr[16];
        kvr[0]  = bf2f(k0.x & 0xFFFFu); kvr[1]  = bf2f(k0.x >> 16);
        kvr[2]  = bf2f(k0.y & 0xFFFFu); kvr[3]  = bf2f(k0.y >> 16);
        kvr[4]  = bf2f(k0.z & 0xFFFFu); kvr[5]  = bf2f(k0.z >> 16);
        kvr[6]  = bf2f(k0.w & 0xFFFFu); kvr[7]  = bf2f(k0.w >> 16);
        kvr[8]  = bf2f(k1.x & 0xFFFFu); kvr[9]  = bf2f(k1.x >> 16);
        kvr[10] = bf2f(k1.y & 0xFFFFu); kvr[11] = bf2f(k1.y >> 16);
        kvr[12] = bf2f(k1.z & 0xFFFFu); kvr[13] = bf2f(k1.z >> 16);
        kvr[14] = bf2f(k1.w & 0xFFFFu); kvr[15] = bf2f(k1.w >> 16);
#pragma unroll
        for (int e = 0; e < 16; e += 2)
            *(float2*)(kvs + t * 20 + e) = make_float2(kvr[e], kvr[e + 1]);

        float lg[32];
#pragma unroll
        for (int j = 0; j < 32; ++j){
            const float* q2r = q2b + j * 16;
            float s = 0.f;
#pragma unroll
            for (int e = 0; e < 16; ++e) s += q2r[e] * kvr[e];
            lg[j] = s;
        }
        float m = lg[0];
#pragma unroll
        for (int j = 1; j < 32; ++j) m = fmaxf(m, lg[j]);
        float s = 0.f;
#pragma unroll
        for (int j = 0; j < 32; ++j){ lg[j] = __expf(lg[j] - m); s += lg[j]; }
        const float inv = 1.f / s;
#pragma unroll
        for (int j = 0; j < 32; ++j) wl[j * 513 + t] = lg[j] * inv;
        __syncthreads();
        // ---- phase B ----
#pragma unroll 4
        for (int it = 0; it < 32; ++it){
            const int nn = sl * 32 + it;
            const float w0 = wl[j0 * 513 + nn];
            const float w1 = wl[j0 * 513 + 513 + nn];
            const float4 ka = *(const float4*)(kvs + nn * 20 + ep * 8);
            const float4 kb = *(const float4*)(kvs + nn * 20 + ep * 8 + 4);
            c2[0][0] += w0 * ka.x; c2[0][1] += w0 * ka.y;
            c2[0][2] += w0 * ka.z; c2[0][3] += w0 * ka.w;
            c2[0][4] += w0 * kb.x; c2[0][5] += w0 * kb.y;
            c2[0][6] += w0 * kb.z; c2[0][7] += w0 * kb.w;
            c2[1][0] += w1 * ka.x; c2[1][1] += w1 * ka.y;
            c2[1][2] += w1 * ka.z; c2[1][3] += w1 * ka.w;
            c2[1][4] += w1 * kb.x; c2[1][5] += w1 * kb.y;
            c2[1][6] += w1 * kb.z; c2[1][7] += w1 * kb.w;
        }
    }
    __syncthreads();
#pragma unroll
    for (int jj = 0; jj < 2; ++jj)
#pragma unroll
        for (int v = 0; v < 8; ++v)
            red[(sl * 32 + (j0 + jj)) * 16 + ep * 8 + v] = c2[jj][v];
    __syncthreads();
    {
        const int j = t >> 4, e = t & 15;
        float sum = 0.f;
#pragma unroll
        for (int s2 = 0; s2 < 16; ++s2) sum += red[(s2 * 32 + j) * 16 + e];
        cnd[j * 16 + e] = sum;
    }
    __syncthreads();
    if (t < 32){
        const int o = t;
        float m2[16];
#pragma unroll
        for (int r = 0; r < 4; ++r)
#pragma unroll
            for (int c = 0; c < 4; ++c){
                float a = 0.f;
#pragma unroll
                for (int k = 0; k < 4; ++k)
                    a += wn[o * 16 + r * 4 + k] * cnd[o * 16 + k * 4 + c];
                m2[r * 4 + c] = a;
            }
        float mu = 0.f;
#pragma unroll
        for (int e = 0; e < 16; ++e) mu += m2[e];
        mu *= (1.f / 16.f);
        float var = 0.f;
#pragma unroll
        for (int e = 0; e < 16; ++e){ const float d = m2[e] - mu; var += d * d; }
        var *= (1.f / 16.f);
        const float invs = rsqrtf(var + EPSF);
#pragma unroll
        for (int e = 0; e < 16; ++e)
            out[(size_t)b * 512 + o * 16 + e] = (m2[e] - mu) * invs * lnw[e] + lnb[e];
    }
}

// ---------------------------------------------------------------------------
extern "C" void kernel_launch(void* const* d_in, const int* in_sizes, int n_in,
                              void* d_out, int out_size, void* d_ws, size_t ws_size,
                              hipStream_t stream){
    const float* cp   = (const float*)d_in[0];   // current_pose [256][64][16][16][16]
    const float* npse = (const float*)d_in[1];   // next_pose    [256][32][16]
    const float* wc   = (const float*)d_in[2];   // w_current    [64][4][4]
    const float* wn   = (const float*)d_in[3];   // w_next       [32][4][4]
    const float* E    = (const float*)d_in[4];   // E_proj       [64][256][128]
    const float* lnw  = (const float*)d_in[5];   // ln_weight    [16]
    const float* lnb  = (const float*)d_in[6];   // ln_bias      [16]
    float* out = (float*)d_out;

    char* ws = (char*)d_ws;
    unsigned short* Ft  = (unsigned short*)ws;                         // 4,194,304 B
    unsigned short* kvb = (unsigned short*)(ws + 4194304);             // 67,108,864 B
    float*          q2g = (float*)(ws + 4194304 + 67108864);           // 524,288 B

    hipLaunchKernelGGL(k_fuseF, dim3(1024), dim3(128), 0, stream, wc, E, Ft);
    hipLaunchKernelGGL(k_q2,    dim3(256),  dim3(512), 0, stream, npse, wn, q2g);
    hipLaunchKernelGGL(k_gemm,  dim3(32, 64), dim3(256), 0, stream, cp, Ft, kvb);
    hipLaunchKernelGGL(k_attn,  dim3(256),  dim3(512), 0, stream, kvb, q2g, wn, lnw, lnb, out);
}

// Round 3
// 133.053 us; speedup vs baseline: 2.9292x; 1.5346x over previous
//
#include <hip/hip_runtime.h>
#include <cstdint>

#define EPSF 1e-5f
#define SCALEF 0.25f  // D^-0.5

typedef __attribute__((ext_vector_type(8))) short bf16x8;   // 8 bf16 = 4 VGPR
typedef __attribute__((ext_vector_type(4))) float f32x4;

union U4B8 { uint4 u; bf16x8 v; unsigned short s[8]; };

__device__ __forceinline__ float bf2f(uint32_t u){
    union { uint32_t i; float f; } v; v.i = u << 16; return v.f;
}
__device__ __forceinline__ uint32_t f2bf(float f){
    union { float f; uint32_t i; } v; v.f = f;
    return (v.i + 0x7FFFu + ((v.i >> 16) & 1u)) >> 16;  // RNE
}

// ws layout (bytes):
//   Ft  : bf16 [64][128 h][256 k]   @ 0           (4,194,304 B)
//   kv  : bf16 [256][8192][16]      @ 4,194,304   (67,108,864 B)
//   q2  : f32  [256][32][16]        @ 71,303,168  (524,288 B)
//   P   : f32  [256][8][32][16]     @ 71,827,456  (4,194,304 B)

// ---------------------------------------------------------------------------
// Kernel 1: fused weight, transposed+bf16:
//   Ft[n2][h][x*16+dd] = bf16( sum_c Wc[(n2&3)*16+x][dd&3][c] *
//                               E[n2][x*16 + (dd>>2)*4 + c][h] )
// ---------------------------------------------------------------------------
__global__ void k_fuseF(const float* __restrict__ wc, const float* __restrict__ E,
                        unsigned short* __restrict__ Ft){
    const int blk = blockIdx.x;
    const int n2 = blk >> 4, x = blk & 15;
    const int h = threadIdx.x;
    const int j = (n2 & 3) * 16 + x;
    float w[16];
#pragma unroll
    for (int t = 0; t < 16; ++t) w[t] = wc[j * 16 + t];
    const float* Eb = E + ((size_t)n2 * 256 + x * 16) * 128 + h;
    float e[16];
#pragma unroll
    for (int t = 0; t < 16; ++t) e[t] = Eb[(size_t)t * 128];
    uint32_t pk[8];
#pragma unroll
    for (int q = 0; q < 8; ++q){
        uint32_t both[2];
#pragma unroll
        for (int half = 0; half < 2; ++half){
            const int dd = q * 2 + half;
            const int r = dd >> 2, k = dd & 3;
            float acc = 0.f;
#pragma unroll
            for (int c = 0; c < 4; ++c) acc += w[k * 4 + c] * e[r * 4 + c];
            both[half] = f2bf(acc);
        }
        pk[q] = both[0] | (both[1] << 16);
    }
    unsigned short* dst = Ft + (size_t)n2 * 32768 + (size_t)h * 256 + x * 16;
    ((uint4*)dst)[0] = make_uint4(pk[0], pk[1], pk[2], pk[3]);
    ((uint4*)dst)[1] = make_uint4(pk[4], pk[5], pk[6], pk[7]);
}

// ---------------------------------------------------------------------------
// Kernel 2: q2[b][o][r*4+c] = SCALE * sum_k wn[o][r][k] * next_pose[b][o][k*4+c]
// ---------------------------------------------------------------------------
__global__ void k_q2(const float* __restrict__ npse, const float* __restrict__ wn,
                     float* __restrict__ q2g){
    const int b = blockIdx.x;
    const int t = threadIdx.x;           // 0..511
    const int o = t >> 4, d = t & 15, r = d >> 2, c = d & 3;
    float acc = 0.f;
#pragma unroll
    for (int k = 0; k < 4; ++k)
        acc += wn[o * 16 + r * 4 + k] * npse[((size_t)b * 32 + o) * 16 + k * 4 + c];
    q2g[(size_t)b * 512 + t] = acc * SCALEF;
}

// ---------------------------------------------------------------------------
// Kernel 3: MFMA GEMM (unchanged from round 2).
// ---------------------------------------------------------------------------
__global__ __launch_bounds__(256, 3) void k_gemm(const float* __restrict__ cp,
                                                 const unsigned short* __restrict__ Ft,
                                                 unsigned short* __restrict__ kv){
    __shared__ unsigned short As[2][128 * 32];
    __shared__ unsigned short Fs[2][128 * 32];
    const int tid  = threadIdx.x;
    const int lane = tid & 63;
    const int wave = tid >> 6;              // 0..3
    const int wm = wave >> 1, wn = wave & 1;
    const int l15 = lane & 15, g = lane >> 4;
    const int mtile = blockIdx.x;           // 0..31
    const int n2 = blockIdx.y;              // 0..63
    const int n2h = n2 >> 4, y = n2 & 15;

    const float* abase[4];
    int aoff[4];
#pragma unroll
    for (int p = 0; p < 4; ++p){
        const int idx = tid + p * 256;      // 0..1023
        const int m = idx >> 3;             // 0..127
        const int kq = idx & 7;             // k = kq*4
        const int b = mtile * 8 + (m >> 4);
        const int i = (m & 15) * 4 + n2h;
        abase[p] = cp + (size_t)b * 262144 + (size_t)i * 4096 + (size_t)y * 256 + kq * 4;
        aoff[p] = m * 32 + (((kq >> 1) ^ ((m >> 1) & 3)) * 8) + (kq & 1) * 4;
    }
    const unsigned short* bbase[2];
    int boff[2];
#pragma unroll
    for (int p = 0; p < 2; ++p){
        const int idx = tid + p * 256;      // 0..511
        const int h = idx >> 2;             // 0..127
        const int kq4 = idx & 3;            // k = kq4*8
        bbase[p] = Ft + (size_t)n2 * 32768 + (size_t)h * 256 + kq4 * 8;
        boff[p] = h * 32 + ((kq4 ^ ((h >> 1) & 3)) * 8);
    }
    int afoff[4], bfoff[4];
#pragma unroll
    for (int mf = 0; mf < 4; ++mf){
        const int row = wm * 64 + mf * 16 + l15;
        afoff[mf] = row * 32 + ((g ^ ((row >> 1) & 3)) * 8);
    }
#pragma unroll
    for (int nf = 0; nf < 4; ++nf){
        const int row = wn * 64 + nf * 16 + l15;
        bfoff[nf] = row * 32 + ((g ^ ((row >> 1) & 3)) * 8);
    }

    f32x4 acc[4][4];
#pragma unroll
    for (int mf = 0; mf < 4; ++mf)
#pragma unroll
        for (int nf = 0; nf < 4; ++nf) acc[mf][nf] = (f32x4){0.f, 0.f, 0.f, 0.f};

    float4 av[4];
    uint4  bv[2];
#pragma unroll
    for (int p = 0; p < 4; ++p) av[p] = *(const float4*)(abase[p]);
#pragma unroll
    for (int p = 0; p < 2; ++p) bv[p] = *(const uint4*)(bbase[p]);
#pragma unroll
    for (int p = 0; p < 4; ++p){
        ushort4 w4;
        w4.x = (unsigned short)f2bf(av[p].x);
        w4.y = (unsigned short)f2bf(av[p].y);
        w4.z = (unsigned short)f2bf(av[p].z);
        w4.w = (unsigned short)f2bf(av[p].w);
        *(ushort4*)(&As[0][aoff[p]]) = w4;
    }
#pragma unroll
    for (int p = 0; p < 2; ++p) *(uint4*)(&Fs[0][boff[p]]) = bv[p];
    __syncthreads();

    for (int kt = 0; kt < 8; ++kt){
        const int cur = kt & 1;
        if (kt < 7){
#pragma unroll
            for (int p = 0; p < 4; ++p) av[p] = *(const float4*)(abase[p] + (kt + 1) * 32);
#pragma unroll
            for (int p = 0; p < 2; ++p) bv[p] = *(const uint4*)(bbase[p] + (kt + 1) * 32);
        }
        bf16x8 af[4], bfr[4];
#pragma unroll
        for (int mf = 0; mf < 4; ++mf) af[mf] = *(const bf16x8*)(&As[cur][afoff[mf]]);
#pragma unroll
        for (int nf = 0; nf < 4; ++nf) bfr[nf] = *(const bf16x8*)(&Fs[cur][bfoff[nf]]);
#pragma unroll
        for (int nf = 0; nf < 4; ++nf)
#pragma unroll
            for (int mf = 0; mf < 4; ++mf)
                acc[mf][nf] = __builtin_amdgcn_mfma_f32_16x16x32_bf16(af[mf], bfr[nf], acc[mf][nf], 0, 0, 0);
        if (kt < 7){
            const int nxt = cur ^ 1;
#pragma unroll
            for (int p = 0; p < 4; ++p){
                ushort4 w4;
                w4.x = (unsigned short)f2bf(av[p].x);
                w4.y = (unsigned short)f2bf(av[p].y);
                w4.z = (unsigned short)f2bf(av[p].z);
                w4.w = (unsigned short)f2bf(av[p].w);
                *(ushort4*)(&As[nxt][aoff[p]]) = w4;
            }
#pragma unroll
            for (int p = 0; p < 2; ++p) *(uint4*)(&Fs[nxt][boff[p]]) = bv[p];
        }
        __syncthreads();
    }

#pragma unroll
    for (int mf = 0; mf < 4; ++mf)
#pragma unroll
        for (int nf = 0; nf < 4; ++nf){
            ushort4 pk;
            pk.x = (unsigned short)f2bf(acc[mf][nf][0]);
            pk.y = (unsigned short)f2bf(acc[mf][nf][1]);
            pk.z = (unsigned short)f2bf(acc[mf][nf][2]);
            pk.w = (unsigned short)f2bf(acc[mf][nf][3]);
            const size_t base =
                ((size_t)(mtile * 8 + wm * 4 + mf) * 8192 +
                 (size_t)n2 * 128 + wn * 64 + nf * 16 + l15) * 16 + g * 4;
            *(ushort4*)(kv + base) = pk;
        }
}

// ---------------------------------------------------------------------------
// Kernel 4: MFMA routing. grid (256 b, 8 split), block 256 (4 indep waves).
// Wave handles 256 n in 4 chunks of 64. Per chunk:
//   stage: kv rows -> kvA [64n][16e + 16 zero-e] (80B rows, for logits A)
//                  -> kvT [16e][64n]             (136B rows, for PV B)
//   logits (per 16n): D[n,j] = mfma(kvA-frag, q2-regs)  (K=e, zero-padded)
//   softmax over j: no max-sub (|logits|<0.1), 4-shfl tree sum, w=e/d
//   w -> wT [32j][64n] bf16 (144B rows) via 8x ds_write_b16
//   PV (K=32 n, x2): acc[jh] = mfma(wT-frag, kvT-frag, acc)
// Partials P[b][split][32][16] f32; k_fin reduces.
// ---------------------------------------------------------------------------
__global__ __launch_bounds__(256) void k_attn(const unsigned short* __restrict__ kv,
                                              const float* __restrict__ q2g,
                                              float* __restrict__ P){
    __shared__ __align__(16) char smem[47616];   // 4 waves x 11904 B
    const int tid = threadIdx.x;
    const int w = tid >> 6, lane = tid & 63;
    const int l15 = lane & 15, g = lane >> 4;
    const int b = blockIdx.x, sp = blockIdx.y;

    char* wb = smem + w * 11904;
    char* kvA = wb;           // [64 n][80 B]: bytes 0..31 = e0..15, 32..63 = 0
    char* kvT = wb + 5120;    // [16 e][136 B]: n*2
    char* wT  = wb + 7296;    // [32 j][144 B]: n*2

    // zero kvA pad-e region once (lane i owns row i)
    *(uint4*)(kvA + lane * 80 + 32) = make_uint4(0u, 0u, 0u, 0u);
    *(uint4*)(kvA + lane * 80 + 48) = make_uint4(0u, 0u, 0u, 0u);

    // q2 B-frags in regs: lane holds q2[j=jh*16+l15][e=g*8+i], zero for g>=2
    U4B8 bq[2];
#pragma unroll
    for (int jh = 0; jh < 2; ++jh){
        if (g < 2){
            const float* src = q2g + (size_t)b * 512 + (size_t)(jh * 16 + l15) * 16 + g * 8;
            const float4 a = *(const float4*)src;
            const float4 c = *(const float4*)(src + 4);
            bq[jh].u.x = f2bf(a.x) | (f2bf(a.y) << 16);
            bq[jh].u.y = f2bf(a.z) | (f2bf(a.w) << 16);
            bq[jh].u.z = f2bf(c.x) | (f2bf(c.y) << 16);
            bq[jh].u.w = f2bf(c.z) | (f2bf(c.w) << 16);
        } else {
            bq[jh].u = make_uint4(0u, 0u, 0u, 0u);
        }
    }

    f32x4 acc[2];
    acc[0] = (f32x4){0.f, 0.f, 0.f, 0.f};
    acc[1] = (f32x4){0.f, 0.f, 0.f, 0.f};
    const f32x4 zf = (f32x4){0.f, 0.f, 0.f, 0.f};

    const int nbase0 = sp * 1024 + w * 256;
    for (int c = 0; c < 4; ++c){
        const int nb = nbase0 + c * 64;
        // ---- stage 64 kv rows ----
#pragma unroll
        for (int p = 0; p < 2; ++p){
            const int idx = p * 64 + lane;
            const int nl = idx >> 1, g2 = idx & 1;
            U4B8 v;
            v.u = *(const uint4*)(kv + ((size_t)b * 8192 + nb + nl) * 16 + g2 * 8);
            *(uint4*)(kvA + nl * 80 + g2 * 16) = v.u;
#pragma unroll
            for (int i = 0; i < 8; ++i)
                *(unsigned short*)(kvT + (g2 * 8 + i) * 136 + nl * 2) = v.s[i];
        }
        // ---- logits + softmax per 16n subtile ----
#pragma unroll
        for (int t = 0; t < 4; ++t){
            const int nt = t * 16;
            U4B8 af;
            af.u = *(const uint4*)(kvA + (nt + l15) * 80 + g * 16);
            f32x4 s0 = __builtin_amdgcn_mfma_f32_16x16x32_bf16(af.v, bq[0].v, zf, 0, 0, 0);
            f32x4 s1 = __builtin_amdgcn_mfma_f32_16x16x32_bf16(af.v, bq[1].v, zf, 0, 0, 0);
            float e0[4], e1[4], dinv[4];
#pragma unroll
            for (int r = 0; r < 4; ++r){ e0[r] = __expf(s0[r]); e1[r] = __expf(s1[r]); }
#pragma unroll
            for (int r = 0; r < 4; ++r){
                float tmp = e0[r] + e1[r];
                tmp += __shfl_xor(tmp, 1);
                tmp += __shfl_xor(tmp, 2);
                tmp += __shfl_xor(tmp, 4);
                tmp += __shfl_xor(tmp, 8);
                dinv[r] = 1.f / tmp;
            }
            // w -> wT[j][n] (j = jh*16+l15 rows; n = nt+g*4+r cols)
#pragma unroll
            for (int r = 0; r < 4; ++r){
                const int ncol = nt + g * 4 + r;
                *(unsigned short*)(wT + (l15)      * 144 + ncol * 2) = (unsigned short)f2bf(e0[r] * dinv[r]);
                *(unsigned short*)(wT + (16 + l15) * 144 + ncol * 2) = (unsigned short)f2bf(e1[r] * dinv[r]);
            }
        }
        // ---- PV: cand[j][e] += sum_n w[j][n] kv[n][e], K=32 x2 ----
#pragma unroll
        for (int kb = 0; kb < 2; ++kb){
            U4B8 pb;
            const uint2 lo = *(const uint2*)(kvT + l15 * 136 + kb * 64 + g * 16);
            const uint2 hi = *(const uint2*)(kvT + l15 * 136 + kb * 64 + g * 16 + 8);
            pb.u = make_uint4(lo.x, lo.y, hi.x, hi.y);
#pragma unroll
            for (int jh = 0; jh < 2; ++jh){
                U4B8 pa;
                pa.u = *(const uint4*)(wT + (jh * 16 + l15) * 144 + kb * 64 + g * 16);
                acc[jh] = __builtin_amdgcn_mfma_f32_16x16x32_bf16(pa.v, pb.v, acc[jh], 0, 0, 0);
            }
        }
    }

    // ---- epilogue: per-wave partial [32 j][16 e] into own LDS slice, then block sum
    float* red = (float*)wb;   // aliases kvA (done with it)
#pragma unroll
    for (int jh = 0; jh < 2; ++jh)
#pragma unroll
        for (int r = 0; r < 4; ++r)
            red[(jh * 16 + g * 4 + r) * 16 + l15] = acc[jh][r];
    __syncthreads();
#pragma unroll
    for (int q = 0; q < 2; ++q){
        const int idx = tid + q * 256;   // j*16+e
        float s = 0.f;
#pragma unroll
        for (int ww = 0; ww < 4; ++ww) s += ((float*)(smem + ww * 11904))[idx];
        P[((size_t)b * 8 + sp) * 512 + idx] = s;
    }
}

// ---------------------------------------------------------------------------
// Kernel 5: reduce 8 splits, w_next transform, LayerNorm, store.
// ---------------------------------------------------------------------------
__global__ __launch_bounds__(512) void k_fin(const float* __restrict__ P,
                                             const float* __restrict__ wn,
                                             const float* __restrict__ lnw,
                                             const float* __restrict__ lnb,
                                             float* __restrict__ out){
    __shared__ float cnd[512];
    const int b = blockIdx.x, t = threadIdx.x;
    float s = 0.f;
#pragma unroll
    for (int sp = 0; sp < 8; ++sp) s += P[((size_t)b * 8 + sp) * 512 + t];
    cnd[t] = s;
    __syncthreads();
    if (t < 32){
        const int o = t;
        float m2[16];
#pragma unroll
        for (int r = 0; r < 4; ++r)
#pragma unroll
            for (int c = 0; c < 4; ++c){
                float a = 0.f;
#pragma unroll
                for (int k = 0; k < 4; ++k)
                    a += wn[o * 16 + r * 4 + k] * cnd[o * 16 + k * 4 + c];
                m2[r * 4 + c] = a;
            }
        float mu = 0.f;
#pragma unroll
        for (int e = 0; e < 16; ++e) mu += m2[e];
        mu *= (1.f / 16.f);
        float var = 0.f;
#pragma unroll
        for (int e = 0; e < 16; ++e){ const float d = m2[e] - mu; var += d * d; }
        var *= (1.f / 16.f);
        const float invs = rsqrtf(var + EPSF);
#pragma unroll
        for (int e = 0; e < 16; ++e)
            out[(size_t)b * 512 + o * 16 + e] = (m2[e] - mu) * invs * lnw[e] + lnb[e];
    }
}

// ---------------------------------------------------------------------------
extern "C" void kernel_launch(void* const* d_in, const int* in_sizes, int n_in,
                              void* d_out, int out_size, void* d_ws, size_t ws_size,
                              hipStream_t stream){
    const float* cp   = (const float*)d_in[0];   // current_pose [256][64][16][16][16]
    const float* npse = (const float*)d_in[1];   // next_pose    [256][32][16]
    const float* wc   = (const float*)d_in[2];   // w_current    [64][4][4]
    const float* wn   = (const float*)d_in[3];   // w_next       [32][4][4]
    const float* E    = (const float*)d_in[4];   // E_proj       [64][256][128]
    const float* lnw  = (const float*)d_in[5];   // ln_weight    [16]
    const float* lnb  = (const float*)d_in[6];   // ln_bias      [16]
    float* out = (float*)d_out;

    char* ws = (char*)d_ws;
    unsigned short* Ft  = (unsigned short*)ws;                         // 4,194,304 B
    unsigned short* kvb = (unsigned short*)(ws + 4194304);             // 67,108,864 B
    float*          q2g = (float*)(ws + 71303168);                     // 524,288 B
    float*          Pp  = (float*)(ws + 71827456);                     // 4,194,304 B

    hipLaunchKernelGGL(k_fuseF, dim3(1024), dim3(128), 0, stream, wc, E, Ft);
    hipLaunchKernelGGL(k_q2,    dim3(256),  dim3(512), 0, stream, npse, wn, q2g);
    hipLaunchKernelGGL(k_gemm,  dim3(32, 64), dim3(256), 0, stream, cp, Ft, kvb);
    hipLaunchKernelGGL(k_attn,  dim3(256, 8), dim3(256), 0, stream, kvb, q2g, Pp);
    hipLaunchKernelGGL(k_fin,   dim3(256),  dim3(512), 0, stream, Pp, wn, lnw, lnb, out);
}